// Round 5
// baseline (523.153 us; speedup 1.0000x reference)
//
#include <hip/hip_runtime.h>
#include <hip/hip_bf16.h>

// Fully fused MLP: 32 -> 64 -> (4x) 64 -> 3, relu hidden, sigmoid out.
// bf16 MFMA (16x16x32), fp32 accum, operand-swapped (D[neuron][point] = W*H).
// Point index is lane-invariant across layers; neuron relabeling pi baked into
// next-layer weight columns at prep time -> lane-local layer handoff, no LDS
// round-trip for activations.
//
// Round-5: round 4 (halved LDS traffic) was NEUTRAL -> not LDS-throughput-bound.
// MFMA pipe 19.7us, LDS pipe 18.9us, dur 57us, no pipe >40% busy => latency-bound,
// too few waves (4/SIMD; LDS image caps 512-thr blocks at 2/CU). Fix: 1024-thread
// blocks share one image among 16 waves -> 512 blocks -> 2 blocks/CU -> 8 waves/SIMD.
// Per-CU MFMA/LDS/VALU work unchanged; only concurrency doubles.
//
// Frag map: 0..3 W_in[nt] | 4..35 W_hid[L][nt][f] | 36..37 W_out[f]
//           38..41 b_in[nt] | 42..57 b_hid[L][nt] | 58 b_out

typedef __attribute__((ext_vector_type(8))) short bf16x8;
typedef __attribute__((ext_vector_type(4))) float f32x4;

#define NFRAG 59
#define IMG_U4 (NFRAG * 64)          // 3776 uint4 = 60416 B

struct F3 { float a, b, c; };        // 12B packed output store

// packed f32x2 -> bf16x2, RNE, 1 instruction. lo = low 16 bits.
__device__ __forceinline__ unsigned cvtpk(float lo, float hi) {
    unsigned r;
    asm("v_cvt_pk_bf16_f32 %0, %1, %2" : "=v"(r) : "v"(lo), "v"(hi));
    return r;
}

// inverse of the neuron relabeling pi: k-slot s -> actual neuron index
__device__ __forceinline__ int pinv(int s) {
    return ((s >> 5) & 1) * 32 + ((s >> 2) & 1) * 16 + ((s >> 3) & 3) * 4 + (s & 3);
}

// value of image slot (frag F, lane) computed from the fp32 weights
__device__ uint4 frag_value(int F, int lane,
        const float* __restrict__ W_in,  const float* __restrict__ b_in,
        const float* __restrict__ W_hid, const float* __restrict__ b_hid,
        const float* __restrict__ W_out, const float* __restrict__ b_out) {
    const int j = lane & 15, g = lane >> 4;
    uint4 r = {0u, 0u, 0u, 0u};
    if (F < 4) {                                   // W_in A-frag, natural k
        const float* row = W_in + (F * 16 + j) * 32 + 8 * g;
        r.x = cvtpk(row[0], row[1]); r.y = cvtpk(row[2], row[3]);
        r.z = cvtpk(row[4], row[5]); r.w = cvtpk(row[6], row[7]);
    } else if (F < 36) {                           // W_hid A-frag, pi-relabeled k
        int q = F - 4, L = q >> 3, nt = (q >> 1) & 3, f = q & 1;
        const float* row = W_hid + (L * 64 + nt * 16 + j) * 64;
        int s0 = 32 * f + 8 * g;
        r.x = cvtpk(row[pinv(s0 + 0)], row[pinv(s0 + 1)]);
        r.y = cvtpk(row[pinv(s0 + 2)], row[pinv(s0 + 3)]);
        r.z = cvtpk(row[pinv(s0 + 4)], row[pinv(s0 + 5)]);
        r.w = cvtpk(row[pinv(s0 + 6)], row[pinv(s0 + 7)]);
    } else if (F < 38) {                           // W_out A-frag (rows 3..15 zero)
        int f = F - 36;
        if (j < 3) {
            const float* row = W_out + j * 64;
            int s0 = 32 * f + 8 * g;
            r.x = cvtpk(row[pinv(s0 + 0)], row[pinv(s0 + 1)]);
            r.y = cvtpk(row[pinv(s0 + 2)], row[pinv(s0 + 3)]);
            r.z = cvtpk(row[pinv(s0 + 4)], row[pinv(s0 + 5)]);
            r.w = cvtpk(row[pinv(s0 + 6)], row[pinv(s0 + 7)]);
        }
    } else {                                       // bias C-frags: f32x4, row = 4g+rr
        union { uint4 u; float f[4]; } t;
        if (F < 42) {
            int nt = F - 38;
#pragma unroll
            for (int rr = 0; rr < 4; ++rr) t.f[rr] = b_in[nt * 16 + 4 * g + rr];
        } else if (F < 58) {
            int q = F - 42, L = q >> 2, nt = q & 3;
#pragma unroll
            for (int rr = 0; rr < 4; ++rr) t.f[rr] = b_hid[L * 64 + nt * 16 + 4 * g + rr];
        } else {
#pragma unroll
            for (int rr = 0; rr < 4; ++rr) t.f[rr] = (4 * g + rr < 3) ? b_out[4 * g + rr] : 0.f;
        }
        r = t.u;
    }
    return r;
}

__global__ void prep_kernel(const float* __restrict__ W_in,  const float* __restrict__ b_in,
                            const float* __restrict__ W_hid, const float* __restrict__ b_hid,
                            const float* __restrict__ W_out, const float* __restrict__ b_out,
                            uint4* __restrict__ img) {
    img[blockIdx.x * 64 + threadIdx.x] =
        frag_value(blockIdx.x, threadIdx.x, W_in, b_in, W_hid, b_hid, W_out, b_out);
}

// relu + lane-local pi-pack: acc[4] (f32x4) -> h[2] (bf16x8)
__device__ __forceinline__ void relu_pack(const f32x4 a[4], bf16x8 h[2]) {
#pragma unroll
    for (int f = 0; f < 2; ++f) {
        union { bf16x8 v; unsigned u[4]; } t;
        t.u[0] = cvtpk(fmaxf(a[2 * f][0], 0.f), fmaxf(a[2 * f][1], 0.f));
        t.u[1] = cvtpk(fmaxf(a[2 * f][2], 0.f), fmaxf(a[2 * f][3], 0.f));
        t.u[2] = cvtpk(fmaxf(a[2 * f + 1][0], 0.f), fmaxf(a[2 * f + 1][1], 0.f));
        t.u[3] = cvtpk(fmaxf(a[2 * f + 1][2], 0.f), fmaxf(a[2 * f + 1][3], 0.f));
        h[f] = t.v;
    }
}

#define MFMA(a, b, c) __builtin_amdgcn_mfma_f32_16x16x32_bf16((a), (b), (c), 0, 0, 0)

template<bool FAST>
__global__ __launch_bounds__(1024, 8) void mlp_kernel(
        const float* __restrict__ x, const uint4* __restrict__ img,
        const float* __restrict__ gW_in,  const float* __restrict__ gb_in,
        const float* __restrict__ gW_hid, const float* __restrict__ gb_hid,
        const float* __restrict__ gW_out, const float* __restrict__ gb_out,
        float* __restrict__ out) {
    __shared__ uint4 simg[IMG_U4];
    const int tid = threadIdx.x;

    if (FAST) {
#pragma unroll
        for (int i = 0; i < 4; ++i) {
            int idx = tid + i * 1024;
            if (idx < IMG_U4) simg[idx] = img[idx];
        }
    } else {
        for (int idx = tid; idx < IMG_U4; idx += 1024)
            simg[idx] = frag_value(idx >> 6, idx & 63,
                                   gW_in, gb_in, gW_hid, gb_hid, gW_out, gb_out);
    }

    const int wave = tid >> 6, lane = tid & 63;
    const int j = lane & 15, g = lane >> 4;
    const int base = (blockIdx.x * 16 + wave) * 128;   // 16 waves * 128 points

    // iter-0 x load issued before the barrier (hides under staging)
    f32x4 raw[4][2];
    {
        const float* xp = x + (size_t)(base + j) * 32 + 8 * g;
#pragma unroll
        for (int t = 0; t < 4; ++t) {
            raw[t][0] = *(const f32x4*)(xp + t * 512);
            raw[t][1] = *(const f32x4*)(xp + t * 512 + 4);
        }
    }
    __syncthreads();

    const uint4* lp = &simg[lane];     // frag F at lp[F*64]: lane*16 + imm, conflict-free

#pragma unroll 1
    for (int it = 0; it < 2; ++it) {
        const int p0 = base + it * 64;

        // pack current x into B-frags (raw regs die here)
        bf16x8 xf[4];
#pragma unroll
        for (int t = 0; t < 4; ++t) {
            union { bf16x8 v; unsigned u[4]; } a;
            a.u[0] = cvtpk(raw[t][0][0], raw[t][0][1]);
            a.u[1] = cvtpk(raw[t][0][2], raw[t][0][3]);
            a.u[2] = cvtpk(raw[t][1][0], raw[t][1][1]);
            a.u[3] = cvtpk(raw[t][1][2], raw[t][1][3]);
            xf[t] = a.v;
        }

        // ======== input layer: all 4 tiles ========
        bf16x8 hfrag[4][2];
        {
            f32x4 acc[4][4];
#pragma unroll
            for (int nt = 0; nt < 4; ++nt) {
                bf16x8 w  = *(const bf16x8*)&lp[nt * 64];
                f32x4  bz = *(const f32x4*)&lp[(38 + nt) * 64];
#pragma unroll
                for (int t = 0; t < 4; ++t)
                    acc[t][nt] = MFMA(w, xf[t], bz);
            }
#pragma unroll
            for (int t = 0; t < 4; ++t) relu_pack(acc[t], hfrag[t]);
        }

        // ======== 4 hidden layers: weights read once, tiles pair-staged ========
#pragma unroll
        for (int L = 0; L < 4; ++L) {
            const int wb = (4 + L * 8) * 64;
            const int bb = (42 + L * 4) * 64;
            bf16x8 w0[4], w1[4]; f32x4 bz[4];
#pragma unroll
            for (int nt = 0; nt < 4; ++nt) {
                w0[nt] = *(const bf16x8*)&lp[wb + (2 * nt) * 64];
                w1[nt] = *(const bf16x8*)&lp[wb + (2 * nt + 1) * 64];
                bz[nt] = *(const f32x4*)&lp[bb + nt * 64];
            }
#pragma unroll
            for (int pr = 0; pr < 2; ++pr) {
                f32x4 pa[2][4];
#pragma unroll
                for (int q = 0; q < 2; ++q)
#pragma unroll
                    for (int nt = 0; nt < 4; ++nt)
                        pa[q][nt] = MFMA(w0[nt], hfrag[2 * pr + q][0], bz[nt]);
#pragma unroll
                for (int q = 0; q < 2; ++q)
#pragma unroll
                    for (int nt = 0; nt < 4; ++nt)
                        pa[q][nt] = MFMA(w1[nt], hfrag[2 * pr + q][1], pa[q][nt]);
#pragma unroll
                for (int q = 0; q < 2; ++q) relu_pack(pa[q], hfrag[2 * pr + q]);
            }
        }

        // ======== output layer ========
        bf16x8 wo0 = *(const bf16x8*)&lp[36 * 64];
        bf16x8 wo1 = *(const bf16x8*)&lp[37 * 64];
        f32x4  bo  = *(const f32x4*)&lp[58 * 64];
        f32x4 z[4];
#pragma unroll
        for (int t = 0; t < 4; ++t) {
            f32x4 tmp = MFMA(wo0, hfrag[t][0], bo);
            z[t] = MFMA(wo1, hfrag[t][1], tmp);
        }

        // prefetch next iter's x (raw regs were dead since pack)
        {
            const int pn = (it < 1) ? p0 + 64 : p0;
            const float* xp = x + (size_t)(pn + j) * 32 + 8 * g;
#pragma unroll
            for (int t = 0; t < 4; ++t) {
                raw[t][0] = *(const f32x4*)(xp + t * 512);
                raw[t][1] = *(const f32x4*)(xp + t * 512 + 4);
            }
        }

        // sigmoid + packed 12B stores (rows 0..2 live in g==0)
        if (g == 0) {
            float* ob = out + (size_t)(p0 + j) * 3;
#pragma unroll
            for (int t = 0; t < 4; ++t) {
                F3 v;
                v.a = __builtin_amdgcn_rcpf(1.f + __expf(-z[t][0]));
                v.b = __builtin_amdgcn_rcpf(1.f + __expf(-z[t][1]));
                v.c = __builtin_amdgcn_rcpf(1.f + __expf(-z[t][2]));
                *(F3*)(ob + t * 48) = v;
            }
        }
    }
}

extern "C" void kernel_launch(void* const* d_in, const int* in_sizes, int n_in,
                              void* d_out, int out_size, void* d_ws, size_t ws_size,
                              hipStream_t stream) {
    const float* x     = (const float*)d_in[0];
    const float* W_in  = (const float*)d_in[1];
    const float* b_in  = (const float*)d_in[2];
    const float* W_hid = (const float*)d_in[3];
    const float* b_hid = (const float*)d_in[4];
    const float* W_out = (const float*)d_in[5];
    const float* b_out = (const float*)d_in[6];
    float* out = (float*)d_out;

    int n = in_sizes[0] / 32;              // 1<<20 points
    int nblocks = n / 2048;                // 16 waves * 128 points per block = 512 blocks

    if (ws_size >= (size_t)IMG_U4 * 16) {
        hipLaunchKernelGGL(prep_kernel, dim3(NFRAG), dim3(64), 0, stream,
                           W_in, b_in, W_hid, b_hid, W_out, b_out, (uint4*)d_ws);
        hipLaunchKernelGGL((mlp_kernel<true>), dim3(nblocks), dim3(1024), 0, stream,
                           x, (const uint4*)d_ws,
                           W_in, b_in, W_hid, b_hid, W_out, b_out, out);
    } else {
        hipLaunchKernelGGL((mlp_kernel<false>), dim3(nblocks), dim3(1024), 0, stream,
                           x, (const uint4*)d_ws,
                           W_in, b_in, W_hid, b_hid, W_out, b_out, out);
    }
}

// Round 7
// 56.411 us; speedup vs baseline: 9.2740x; 9.2740x over previous
//
#include <hip/hip_runtime.h>
#include <hip/hip_bf16.h>

// Fully fused MLP: 32 -> 64 -> (4x) 64 -> 3, relu hidden, sigmoid out.
// bf16 MFMA (16x16x32), fp32 accum, operand-swapped (D[neuron][point] = W*H).
// Point index is lane-invariant across layers; neuron relabeling pi baked into
// next-layer weight columns at prep time -> lane-local layer handoff.
//
// Round-7: round 6 NaN'd after TWO simultaneous changes (pk_max_i16 relu +
// compact bias). Bias compaction re-verified exhaustively (alignment, values,
// coverage) -> clean. Unique NaN-creation mechanism is the raw-asm v_pk_max_i16
// (VOP3P modifier defaults could leave half the dst unwritten -> stale garbage
// bits). BISECT: revert relu to proven fmaxf-then-cvtpk, KEEP compact biases.
//
// Frag map (weights): 0..3 W_in[nt] | 4..35 W_hid[L][nt][f] | 36..37 W_out[f]
// Bias floats at BIAS_F32: [0..63] b_in | [64..319] b_hid | [320..335] b_out+pad

typedef __attribute__((ext_vector_type(8))) short bf16x8;
typedef __attribute__((ext_vector_type(4))) float f32x4;

#define NWFRAG 38
#define BIAS_F32 9728                 // float offset of bias region (= 38*1024/4)
#define IMG_BYTES 40256               // 38912 weight bytes + 336*4 bias bytes
#define IMG_U4 2516

struct F3 { float a, b, c; };         // 12B packed output store

// packed f32x2 -> bf16x2, RNE, 1 instruction. lo = low 16 bits.
__device__ __forceinline__ unsigned cvtpk(float lo, float hi) {
    unsigned r;
    asm("v_cvt_pk_bf16_f32 %0, %1, %2" : "=v"(r) : "v"(lo), "v"(hi));
    return r;
}

// inverse of the neuron relabeling pi: k-slot s -> actual neuron index
__device__ __forceinline__ int pinv(int s) {
    return ((s >> 5) & 1) * 32 + ((s >> 2) & 1) * 16 + ((s >> 3) & 3) * 4 + (s & 3);
}

// weight frag value (frag F < 38, lane)
__device__ uint4 frag_value_w(int F, int lane,
        const float* __restrict__ W_in, const float* __restrict__ W_hid,
        const float* __restrict__ W_out) {
    const int j = lane & 15, g = lane >> 4;
    uint4 r = {0u, 0u, 0u, 0u};
    if (F < 4) {                                   // W_in A-frag, natural k
        const float* row = W_in + (F * 16 + j) * 32 + 8 * g;
        r.x = cvtpk(row[0], row[1]); r.y = cvtpk(row[2], row[3]);
        r.z = cvtpk(row[4], row[5]); r.w = cvtpk(row[6], row[7]);
    } else if (F < 36) {                           // W_hid A-frag, pi-relabeled k
        int q = F - 4, L = q >> 3, nt = (q >> 1) & 3, f = q & 1;
        const float* row = W_hid + (L * 64 + nt * 16 + j) * 64;
        int s0 = 32 * f + 8 * g;
        r.x = cvtpk(row[pinv(s0 + 0)], row[pinv(s0 + 1)]);
        r.y = cvtpk(row[pinv(s0 + 2)], row[pinv(s0 + 3)]);
        r.z = cvtpk(row[pinv(s0 + 4)], row[pinv(s0 + 5)]);
        r.w = cvtpk(row[pinv(s0 + 6)], row[pinv(s0 + 7)]);
    } else {                                       // W_out A-frag (rows 3..15 zero)
        int f = F - 36;
        if (j < 3) {
            const float* row = W_out + j * 64;
            int s0 = 32 * f + 8 * g;
            r.x = cvtpk(row[pinv(s0 + 0)], row[pinv(s0 + 1)]);
            r.y = cvtpk(row[pinv(s0 + 2)], row[pinv(s0 + 3)]);
            r.z = cvtpk(row[pinv(s0 + 4)], row[pinv(s0 + 5)]);
            r.w = cvtpk(row[pinv(s0 + 6)], row[pinv(s0 + 7)]);
        }
    }
    return r;
}

__device__ __forceinline__ float bias_val(int idx,
        const float* __restrict__ b_in, const float* __restrict__ b_hid,
        const float* __restrict__ b_out) {
    if (idx < 64)  return b_in[idx];
    if (idx < 320) return b_hid[idx - 64];
    return (idx - 320 < 3) ? b_out[idx - 320] : 0.f;
}

__global__ void prep_kernel(const float* __restrict__ W_in,  const float* __restrict__ b_in,
                            const float* __restrict__ W_hid, const float* __restrict__ b_hid,
                            const float* __restrict__ W_out, const float* __restrict__ b_out,
                            uint4* __restrict__ img) {
    const int F = blockIdx.x, t = threadIdx.x;
    if (F < NWFRAG) {
        img[F * 64 + t] = frag_value_w(F, t, W_in, W_hid, W_out);
    } else {
        float* fb = (float*)img + BIAS_F32;
        for (int idx = t; idx < 336; idx += 64)
            fb[idx] = bias_val(idx, b_in, b_hid, b_out);
    }
}

// relu + lane-local pi-pack: acc[4] (f32x4) -> h[2] (bf16x8)  [round-4 proven form]
__device__ __forceinline__ void relu_pack(const f32x4 a[4], bf16x8 h[2]) {
#pragma unroll
    for (int f = 0; f < 2; ++f) {
        union { bf16x8 v; unsigned u[4]; } t;
        t.u[0] = cvtpk(fmaxf(a[2 * f][0], 0.f), fmaxf(a[2 * f][1], 0.f));
        t.u[1] = cvtpk(fmaxf(a[2 * f][2], 0.f), fmaxf(a[2 * f][3], 0.f));
        t.u[2] = cvtpk(fmaxf(a[2 * f + 1][0], 0.f), fmaxf(a[2 * f + 1][1], 0.f));
        t.u[3] = cvtpk(fmaxf(a[2 * f + 1][2], 0.f), fmaxf(a[2 * f + 1][3], 0.f));
        h[f] = t.v;
    }
}

#define MFMA(a, b, c) __builtin_amdgcn_mfma_f32_16x16x32_bf16((a), (b), (c), 0, 0, 0)

template<bool FAST>
__global__ __launch_bounds__(512, 4) void mlp_kernel(
        const float* __restrict__ x, const uint4* __restrict__ img,
        const float* __restrict__ gW_in,  const float* __restrict__ gb_in,
        const float* __restrict__ gW_hid, const float* __restrict__ gb_hid,
        const float* __restrict__ gW_out, const float* __restrict__ gb_out,
        float* __restrict__ out) {
    __shared__ uint4 simg[IMG_U4];
    const int tid = threadIdx.x;

    if (FAST) {
#pragma unroll
        for (int i = 0; i < 5; ++i) {
            int idx = tid + i * 512;
            if (idx < IMG_U4) simg[idx] = img[idx];
        }
    } else {
        for (int idx = tid; idx < NWFRAG * 64; idx += 512)
            simg[idx] = frag_value_w(idx >> 6, idx & 63, gW_in, gW_hid, gW_out);
        {
            float* fb = (float*)simg + BIAS_F32;
            for (int idx = tid; idx < 336; idx += 512)
                fb[idx] = bias_val(idx, gb_in, gb_hid, gb_out);
        }
    }

    const int wave = tid >> 6, lane = tid & 63;
    const int j = lane & 15, g = lane >> 4;
    const int base = (blockIdx.x * 8 + wave) * 256;

    // iter-0 x load issued before the barrier (hides under staging)
    f32x4 raw[4][2];
    {
        const float* xp = x + (size_t)(base + j) * 32 + 8 * g;
#pragma unroll
        for (int t = 0; t < 4; ++t) {
            raw[t][0] = *(const f32x4*)(xp + t * 512);
            raw[t][1] = *(const f32x4*)(xp + t * 512 + 4);
        }
    }
    __syncthreads();

    const uint4*  lp = &simg[lane];              // weight frag F at lp[F*64]
    const float*  sb = (const float*)simg + BIAS_F32;

#pragma unroll 1
    for (int it = 0; it < 4; ++it) {
        const int p0 = base + it * 64;

        // pack current x into B-frags (raw regs die here)
        bf16x8 xf[4];
#pragma unroll
        for (int t = 0; t < 4; ++t) {
            union { bf16x8 v; unsigned u[4]; } a;
            a.u[0] = cvtpk(raw[t][0][0], raw[t][0][1]);
            a.u[1] = cvtpk(raw[t][0][2], raw[t][0][3]);
            a.u[2] = cvtpk(raw[t][1][0], raw[t][1][1]);
            a.u[3] = cvtpk(raw[t][1][2], raw[t][1][3]);
            xf[t] = a.v;
        }

        // ======== input layer: all 4 tiles ========
        bf16x8 hfrag[4][2];
        {
            f32x4 acc[4][4];
#pragma unroll
            for (int nt = 0; nt < 4; ++nt) {
                bf16x8 w  = *(const bf16x8*)&lp[nt * 64];
                f32x4  bz = *(const f32x4*)&sb[nt * 16 + 4 * g];
#pragma unroll
                for (int t = 0; t < 4; ++t)
                    acc[t][nt] = MFMA(w, xf[t], bz);
            }
#pragma unroll
            for (int t = 0; t < 4; ++t) relu_pack(acc[t], hfrag[t]);
        }

        // ======== 4 hidden layers: weights read once, tiles pair-staged ========
#pragma unroll
        for (int L = 0; L < 4; ++L) {
            const int wb = (4 + L * 8) * 64;
            bf16x8 w0[4], w1[4]; f32x4 bz[4];
#pragma unroll
            for (int nt = 0; nt < 4; ++nt) {
                w0[nt] = *(const bf16x8*)&lp[wb + (2 * nt) * 64];
                w1[nt] = *(const bf16x8*)&lp[wb + (2 * nt + 1) * 64];
                bz[nt] = *(const f32x4*)&sb[64 + L * 64 + nt * 16 + 4 * g];
            }
#pragma unroll
            for (int pr = 0; pr < 2; ++pr) {
                f32x4 pa[2][4];
#pragma unroll
                for (int q = 0; q < 2; ++q)
#pragma unroll
                    for (int nt = 0; nt < 4; ++nt)
                        pa[q][nt] = MFMA(w0[nt], hfrag[2 * pr + q][0], bz[nt]);
#pragma unroll
                for (int q = 0; q < 2; ++q)
#pragma unroll
                    for (int nt = 0; nt < 4; ++nt)
                        pa[q][nt] = MFMA(w1[nt], hfrag[2 * pr + q][1], pa[q][nt]);
#pragma unroll
                for (int q = 0; q < 2; ++q) relu_pack(pa[q], hfrag[2 * pr + q]);
            }
        }

        // ======== output layer ========
        bf16x8 wo0 = *(const bf16x8*)&lp[36 * 64];
        bf16x8 wo1 = *(const bf16x8*)&lp[37 * 64];
        f32x4  bo  = *(const f32x4*)&sb[320 + 4 * g];   // g>0 rows read zero pad
        f32x4 z[4];
#pragma unroll
        for (int t = 0; t < 4; ++t) {
            f32x4 tmp = MFMA(wo0, hfrag[t][0], bo);
            z[t] = MFMA(wo1, hfrag[t][1], tmp);
        }

        // prefetch next iter's x (raw regs were dead since pack)
        {
            const int pn = (it < 3) ? p0 + 64 : p0;
            const float* xp = x + (size_t)(pn + j) * 32 + 8 * g;
#pragma unroll
            for (int t = 0; t < 4; ++t) {
                raw[t][0] = *(const f32x4*)(xp + t * 512);
                raw[t][1] = *(const f32x4*)(xp + t * 512 + 4);
            }
        }

        // sigmoid + packed 12B stores (rows 0..2 live in g==0)
        if (g == 0) {
            float* ob = out + (size_t)(p0 + j) * 3;
#pragma unroll
            for (int t = 0; t < 4; ++t) {
                F3 v;
                v.a = __builtin_amdgcn_rcpf(1.f + __expf(-z[t][0]));
                v.b = __builtin_amdgcn_rcpf(1.f + __expf(-z[t][1]));
                v.c = __builtin_amdgcn_rcpf(1.f + __expf(-z[t][2]));
                *(F3*)(ob + t * 48) = v;
            }
        }
    }
}

extern "C" void kernel_launch(void* const* d_in, const int* in_sizes, int n_in,
                              void* d_out, int out_size, void* d_ws, size_t ws_size,
                              hipStream_t stream) {
    const float* x     = (const float*)d_in[0];
    const float* W_in  = (const float*)d_in[1];
    const float* b_in  = (const float*)d_in[2];
    const float* W_hid = (const float*)d_in[3];
    const float* b_hid = (const float*)d_in[4];
    const float* W_out = (const float*)d_in[5];
    const float* b_out = (const float*)d_in[6];
    float* out = (float*)d_out;

    int n = in_sizes[0] / 32;              // 1<<20 points
    int nblocks = n / 2048;                // 8 waves * 256 points per block = 512 blocks

    if (ws_size >= (size_t)IMG_BYTES) {
        hipLaunchKernelGGL(prep_kernel, dim3(NWFRAG + 1), dim3(64), 0, stream,
                           W_in, b_in, W_hid, b_hid, W_out, b_out, (uint4*)d_ws);
        hipLaunchKernelGGL((mlp_kernel<true>), dim3(nblocks), dim3(512), 0, stream,
                           x, (const uint4*)d_ws,
                           W_in, b_in, W_hid, b_hid, W_out, b_out, out);
    } else {
        hipLaunchKernelGGL((mlp_kernel<false>), dim3(nblocks), dim3(512), 0, stream,
                           x, (const uint4*)d_ws,
                           W_in, b_in, W_hid, b_hid, W_out, b_out, out);
    }
}

// Round 9
// 46.137 us; speedup vs baseline: 11.3392x; 1.2227x over previous
//
#include <hip/hip_runtime.h>
#include <hip/hip_bf16.h>

// Fully fused MLP: 32 -> 64 -> (4x) 64 -> 3, relu hidden, sigmoid out.
// bf16 MFMA (16x16x32), fp32 accum, operand-swapped (D[neuron][point] = W*H).
// Point index is lane-invariant across layers; neuron relabeling pi baked into
// next-layer weight columns at prep time -> lane-local layer handoff.
//
// Round-9: r8's s_sleep stagger was perf-NULL and broke replay determinism ->
// removed (back to proven r7 base). Remaining levers with distinct mechanisms:
//  G1: s_setprio(1) around MFMA clusters (waves are barrier-free/de-phased ->
//      role diversity exists, the regime where setprio pays).
//  G2: packed relu v_pk_max_i16 with REGISTER zero (r6 used inline-literal 0,
//      whose VOP3P inline-const semantics are ambiguous -> NaN; register form
//      is unambiguous and bit-exact vs fmaxf+cvtpk, incl -0). 24->12 VALU per
//      tile-layer.
//
// Frag map (weights): 0..3 W_in[nt] | 4..35 W_hid[L][nt][f] | 36..37 W_out[f]
// Bias floats at BIAS_F32: [0..63] b_in | [64..319] b_hid | [320..335] b_out+pad

typedef __attribute__((ext_vector_type(8))) short bf16x8;
typedef __attribute__((ext_vector_type(4))) float f32x4;

#define NWFRAG 38
#define BIAS_F32 9728                 // float offset of bias region (= 38*1024/4)
#define IMG_BYTES 40256               // 38912 weight bytes + 336*4 bias bytes
#define IMG_U4 2516

struct F3 { float a, b, c; };         // 12B packed output store

// packed f32x2 -> bf16x2, RNE, 1 instruction. lo = low 16 bits.
__device__ __forceinline__ unsigned cvtpk(float lo, float hi) {
    unsigned r;
    asm("v_cvt_pk_bf16_f32 %0, %1, %2" : "=v"(r) : "v"(lo), "v"(hi));
    return r;
}

// packed bf16x2 relu: int16 max vs 0 is exact relu on bf16 encodings
// (positives order like int16; negatives/-0 have the sign bit set -> clamp
// to +0). Zero passed as a REGISTER operand: both packed halves read 0
// regardless of op_sel_hi defaults (r6's inline-literal form was the NaN bug).
__device__ __forceinline__ unsigned pkrelu(unsigned u, unsigned z) {
    unsigned r;
    asm("v_pk_max_i16 %0, %1, %2" : "=v"(r) : "v"(u), "v"(z));
    return r;
}

// inverse of the neuron relabeling pi: k-slot s -> actual neuron index
__device__ __forceinline__ int pinv(int s) {
    return ((s >> 5) & 1) * 32 + ((s >> 2) & 1) * 16 + ((s >> 3) & 3) * 4 + (s & 3);
}

// weight frag value (frag F < 38, lane)
__device__ uint4 frag_value_w(int F, int lane,
        const float* __restrict__ W_in, const float* __restrict__ W_hid,
        const float* __restrict__ W_out) {
    const int j = lane & 15, g = lane >> 4;
    uint4 r = {0u, 0u, 0u, 0u};
    if (F < 4) {                                   // W_in A-frag, natural k
        const float* row = W_in + (F * 16 + j) * 32 + 8 * g;
        r.x = cvtpk(row[0], row[1]); r.y = cvtpk(row[2], row[3]);
        r.z = cvtpk(row[4], row[5]); r.w = cvtpk(row[6], row[7]);
    } else if (F < 36) {                           // W_hid A-frag, pi-relabeled k
        int q = F - 4, L = q >> 3, nt = (q >> 1) & 3, f = q & 1;
        const float* row = W_hid + (L * 64 + nt * 16 + j) * 64;
        int s0 = 32 * f + 8 * g;
        r.x = cvtpk(row[pinv(s0 + 0)], row[pinv(s0 + 1)]);
        r.y = cvtpk(row[pinv(s0 + 2)], row[pinv(s0 + 3)]);
        r.z = cvtpk(row[pinv(s0 + 4)], row[pinv(s0 + 5)]);
        r.w = cvtpk(row[pinv(s0 + 6)], row[pinv(s0 + 7)]);
    } else {                                       // W_out A-frag (rows 3..15 zero)
        int f = F - 36;
        if (j < 3) {
            const float* row = W_out + j * 64;
            int s0 = 32 * f + 8 * g;
            r.x = cvtpk(row[pinv(s0 + 0)], row[pinv(s0 + 1)]);
            r.y = cvtpk(row[pinv(s0 + 2)], row[pinv(s0 + 3)]);
            r.z = cvtpk(row[pinv(s0 + 4)], row[pinv(s0 + 5)]);
            r.w = cvtpk(row[pinv(s0 + 6)], row[pinv(s0 + 7)]);
        }
    }
    return r;
}

__device__ __forceinline__ float bias_val(int idx,
        const float* __restrict__ b_in, const float* __restrict__ b_hid,
        const float* __restrict__ b_out) {
    if (idx < 64)  return b_in[idx];
    if (idx < 320) return b_hid[idx - 64];
    return (idx - 320 < 3) ? b_out[idx - 320] : 0.f;
}

__global__ void prep_kernel(const float* __restrict__ W_in,  const float* __restrict__ b_in,
                            const float* __restrict__ W_hid, const float* __restrict__ b_hid,
                            const float* __restrict__ W_out, const float* __restrict__ b_out,
                            uint4* __restrict__ img) {
    const int F = blockIdx.x, t = threadIdx.x;
    if (F < NWFRAG) {
        img[F * 64 + t] = frag_value_w(F, t, W_in, W_hid, W_out);
    } else {
        float* fb = (float*)img + BIAS_F32;
        for (int idx = t; idx < 336; idx += 64)
            fb[idx] = bias_val(idx, b_in, b_hid, b_out);
    }
}

// relu + lane-local pi-pack: acc[4] (f32x4) -> h[2] (bf16x8)
// cvtpk first, then packed int16 relu (bit-exact vs fmaxf-then-cvtpk).
__device__ __forceinline__ void relu_pack(const f32x4 a[4], bf16x8 h[2], unsigned z) {
#pragma unroll
    for (int f = 0; f < 2; ++f) {
        union { bf16x8 v; unsigned u[4]; } t;
        t.u[0] = pkrelu(cvtpk(a[2 * f][0], a[2 * f][1]), z);
        t.u[1] = pkrelu(cvtpk(a[2 * f][2], a[2 * f][3]), z);
        t.u[2] = pkrelu(cvtpk(a[2 * f + 1][0], a[2 * f + 1][1]), z);
        t.u[3] = pkrelu(cvtpk(a[2 * f + 1][2], a[2 * f + 1][3]), z);
        h[f] = t.v;
    }
}

#define MFMA(a, b, c) __builtin_amdgcn_mfma_f32_16x16x32_bf16((a), (b), (c), 0, 0, 0)

template<bool FAST>
__global__ __launch_bounds__(512, 4) void mlp_kernel(
        const float* __restrict__ x, const uint4* __restrict__ img,
        const float* __restrict__ gW_in,  const float* __restrict__ gb_in,
        const float* __restrict__ gW_hid, const float* __restrict__ gb_hid,
        const float* __restrict__ gW_out, const float* __restrict__ gb_out,
        float* __restrict__ out) {
    __shared__ uint4 simg[IMG_U4];
    const int tid = threadIdx.x;

    if (FAST) {
#pragma unroll
        for (int i = 0; i < 5; ++i) {
            int idx = tid + i * 512;
            if (idx < IMG_U4) simg[idx] = img[idx];
        }
    } else {
        for (int idx = tid; idx < NWFRAG * 64; idx += 512)
            simg[idx] = frag_value_w(idx >> 6, idx & 63, gW_in, gW_hid, gW_out);
        {
            float* fb = (float*)simg + BIAS_F32;
            for (int idx = tid; idx < 336; idx += 512)
                fb[idx] = bias_val(idx, gb_in, gb_hid, gb_out);
        }
    }

    const int wave = tid >> 6, lane = tid & 63;
    const int j = lane & 15, g = lane >> 4;
    const int base = (blockIdx.x * 8 + wave) * 256;

    // iter-0 x load issued before the barrier (hides under staging)
    f32x4 raw[4][2];
    {
        const float* xp = x + (size_t)(base + j) * 32 + 8 * g;
#pragma unroll
        for (int t = 0; t < 4; ++t) {
            raw[t][0] = *(const f32x4*)(xp + t * 512);
            raw[t][1] = *(const f32x4*)(xp + t * 512 + 4);
        }
    }
    __syncthreads();

    const uint4*  lp = &simg[lane];              // weight frag F at lp[F*64]
    const float*  sb = (const float*)simg + BIAS_F32;
    const unsigned z = 0;                        // register zero for pkrelu

#pragma unroll 1
    for (int it = 0; it < 4; ++it) {
        const int p0 = base + it * 64;

        // pack current x into B-frags (raw regs die here)
        bf16x8 xf[4];
#pragma unroll
        for (int t = 0; t < 4; ++t) {
            union { bf16x8 v; unsigned u[4]; } a;
            a.u[0] = cvtpk(raw[t][0][0], raw[t][0][1]);
            a.u[1] = cvtpk(raw[t][0][2], raw[t][0][3]);
            a.u[2] = cvtpk(raw[t][1][0], raw[t][1][1]);
            a.u[3] = cvtpk(raw[t][1][2], raw[t][1][3]);
            xf[t] = a.v;
        }

        // ======== input layer: all 4 tiles ========
        bf16x8 hfrag[4][2];
        {
            f32x4 acc[4][4];
            __builtin_amdgcn_s_setprio(1);
#pragma unroll
            for (int nt = 0; nt < 4; ++nt) {
                bf16x8 w  = *(const bf16x8*)&lp[nt * 64];
                f32x4  bz = *(const f32x4*)&sb[nt * 16 + 4 * g];
#pragma unroll
                for (int t = 0; t < 4; ++t)
                    acc[t][nt] = MFMA(w, xf[t], bz);
            }
            __builtin_amdgcn_s_setprio(0);
#pragma unroll
            for (int t = 0; t < 4; ++t) relu_pack(acc[t], hfrag[t], z);
        }

        // ======== 4 hidden layers: weights read once, tiles pair-staged ========
#pragma unroll
        for (int L = 0; L < 4; ++L) {
            const int wb = (4 + L * 8) * 64;
            bf16x8 w0[4], w1[4]; f32x4 bz[4];
#pragma unroll
            for (int nt = 0; nt < 4; ++nt) {
                w0[nt] = *(const bf16x8*)&lp[wb + (2 * nt) * 64];
                w1[nt] = *(const bf16x8*)&lp[wb + (2 * nt + 1) * 64];
                bz[nt] = *(const f32x4*)&sb[64 + L * 64 + nt * 16 + 4 * g];
            }
#pragma unroll
            for (int pr = 0; pr < 2; ++pr) {
                f32x4 pa[2][4];
                __builtin_amdgcn_s_setprio(1);
#pragma unroll
                for (int q = 0; q < 2; ++q)
#pragma unroll
                    for (int nt = 0; nt < 4; ++nt)
                        pa[q][nt] = MFMA(w0[nt], hfrag[2 * pr + q][0], bz[nt]);
#pragma unroll
                for (int q = 0; q < 2; ++q)
#pragma unroll
                    for (int nt = 0; nt < 4; ++nt)
                        pa[q][nt] = MFMA(w1[nt], hfrag[2 * pr + q][1], pa[q][nt]);
                __builtin_amdgcn_s_setprio(0);
#pragma unroll
                for (int q = 0; q < 2; ++q) relu_pack(pa[q], hfrag[2 * pr + q], z);
            }
        }

        // ======== output layer ========
        bf16x8 wo0 = *(const bf16x8*)&lp[36 * 64];
        bf16x8 wo1 = *(const bf16x8*)&lp[37 * 64];
        f32x4  bo  = *(const f32x4*)&sb[320 + 4 * g];   // g>0 rows read zero pad
        f32x4 zacc[4];
        __builtin_amdgcn_s_setprio(1);
#pragma unroll
        for (int t = 0; t < 4; ++t) {
            f32x4 tmp = MFMA(wo0, hfrag[t][0], bo);
            zacc[t] = MFMA(wo1, hfrag[t][1], tmp);
        }
        __builtin_amdgcn_s_setprio(0);

        // prefetch next iter's x (raw regs were dead since pack)
        {
            const int pn = (it < 3) ? p0 + 64 : p0;
            const float* xp = x + (size_t)(pn + j) * 32 + 8 * g;
#pragma unroll
            for (int t = 0; t < 4; ++t) {
                raw[t][0] = *(const f32x4*)(xp + t * 512);
                raw[t][1] = *(const f32x4*)(xp + t * 512 + 4);
            }
        }

        // sigmoid + packed 12B stores (rows 0..2 live in g==0)
        if (g == 0) {
            float* ob = out + (size_t)(p0 + j) * 3;
#pragma unroll
            for (int t = 0; t < 4; ++t) {
                F3 v;
                v.a = __builtin_amdgcn_rcpf(1.f + __expf(-zacc[t][0]));
                v.b = __builtin_amdgcn_rcpf(1.f + __expf(-zacc[t][1]));
                v.c = __builtin_amdgcn_rcpf(1.f + __expf(-zacc[t][2]));
                *(F3*)(ob + t * 48) = v;
            }
        }
    }
}

extern "C" void kernel_launch(void* const* d_in, const int* in_sizes, int n_in,
                              void* d_out, int out_size, void* d_ws, size_t ws_size,
                              hipStream_t stream) {
    const float* x     = (const float*)d_in[0];
    const float* W_in  = (const float*)d_in[1];
    const float* b_in  = (const float*)d_in[2];
    const float* W_hid = (const float*)d_in[3];
    const float* b_hid = (const float*)d_in[4];
    const float* W_out = (const float*)d_in[5];
    const float* b_out = (const float*)d_in[6];
    float* out = (float*)d_out;

    int n = in_sizes[0] / 32;              // 1<<20 points
    int nblocks = n / 2048;                // 8 waves * 256 points per block = 512 blocks

    if (ws_size >= (size_t)IMG_BYTES) {
        hipLaunchKernelGGL(prep_kernel, dim3(NWFRAG + 1), dim3(64), 0, stream,
                           W_in, b_in, W_hid, b_hid, W_out, b_out, (uint4*)d_ws);
        hipLaunchKernelGGL((mlp_kernel<true>), dim3(nblocks), dim3(512), 0, stream,
                           x, (const uint4*)d_ws,
                           W_in, b_in, W_hid, b_hid, W_out, b_out, out);
    } else {
        hipLaunchKernelGGL((mlp_kernel<false>), dim3(nblocks), dim3(512), 0, stream,
                           x, (const uint4*)d_ws,
                           W_in, b_in, W_hid, b_hid, W_out, b_out, out);
    }
}